// Round 9
// baseline (166.185 us; speedup 1.0000x reference)
//
#include <hip/hip_runtime.h>

// Problem constants (from reference setup_inputs)
#define BATCH 16
#define CIN   3
#define H     384
#define W     384
#define HW    (H * W)
#define HO    382
#define WO    382
#define WO2   191
#define OFFC  18
#define OOUT  3
#define KTAPS 9

// Padded HWC-float4 layout: 2-px zero halo reproduces OOB-mask semantics.
#define PAD   2
#define HP    (H + 2 * PAD)     // 388
#define WP    (W + 2 * PAD)     // 388

typedef float vf2 __attribute__((ext_vector_type(2)));
struct F3 { float a, b, c; };

static __device__ __forceinline__ vf2 splat2(float s) { vf2 r; r.x = s; r.y = s; return r; }

// ---------------------------------------------------------------------------
// Pass 1a: CHW -> padded HWC float4 (zero halo), 38.5 MB workspace.
__global__ __launch_bounds__(256)
void chw_to_hwc4_kernel(const float* __restrict__ x, float4* __restrict__ xt)
{
    const int gid = blockIdx.x * 256 + threadIdx.x;
    if (gid >= BATCH * HP * WP) return;
    const int b  = gid / (HP * WP);
    const int r2 = gid - b * (HP * WP);
    const int ry = r2 / WP;
    const int rx = r2 - ry * WP;
    const int yi = ry - PAD;
    const int xi = rx - PAD;
    float4 v = make_float4(0.f, 0.f, 0.f, 0.f);
    if ((unsigned)yi < (unsigned)H && (unsigned)xi < (unsigned)W) {
        const float* xb = x + (size_t)b * (CIN * HW);
        const int p = yi * W + xi;
        v.x = xb[p];
        v.y = xb[HW + p];
        v.z = xb[2 * HW + p];
    }
    xt[gid] = v;
}

// ---------------------------------------------------------------------------
// Pass 2a: pixel-PAIR kernel on padded float4 HWC.
// Two horizontally adjacent pixels per thread; all shared-weight math done in
// float2 ext-vectors so the compiler emits v_pk_fma_f32 (dual fp32/issue).
// No masks (halo zeros), per-tap immediate consumption, scalar-cache weights.
__global__ __launch_bounds__(256)
void deform_pair_kernel(const float4* __restrict__ xt,
                        const float* __restrict__ conv_w,
                        const float* __restrict__ conv_b,
                        const float* __restrict__ dcn_w,
                        const float* __restrict__ dcn_b,
                        float* __restrict__ out)
{
    const int total = BATCH * HO * WO2;
    const int gid = blockIdx.x * 256 + threadIdx.x;
    if (gid >= total) return;

    const int g   = gid % WO2;
    const int tmp = gid / WO2;
    const int ho  = tmp % HO;
    const int b   = tmp / HO;
    const int wo  = 2 * g;

    const float4* xtb = xt + (size_t)b * (HP * WP);

    // Patch for the pair: rows ho..ho+2, cols wo..wo+3 (12 float4 loads).
    // xp2[i][j][c] = channel c at kernel pos (i,j) for {px0, px1}.
    vf2 xp2[3][3][CIN];
    #pragma unroll
    for (int i = 0; i < 3; ++i) {
        const float4* row = xtb + (ho + i + PAD) * WP + (wo + PAD);
        const float4 r0 = row[0];
        const float4 r1 = row[1];
        const float4 r2 = row[2];
        const float4 r3 = row[3];
        xp2[i][0][0].x = r0.x; xp2[i][0][0].y = r1.x;
        xp2[i][0][1].x = r0.y; xp2[i][0][1].y = r1.y;
        xp2[i][0][2].x = r0.z; xp2[i][0][2].y = r1.z;
        xp2[i][1][0].x = r1.x; xp2[i][1][0].y = r2.x;
        xp2[i][1][1].x = r1.y; xp2[i][1][1].y = r2.y;
        xp2[i][1][2].x = r1.z; xp2[i][1][2].y = r2.z;
        xp2[i][2][0].x = r2.x; xp2[i][2][0].y = r3.x;
        xp2[i][2][1].x = r2.y; xp2[i][2][1].y = r3.y;
        xp2[i][2][2].x = r2.z; xp2[i][2][2].y = r3.z;
    }

    // Offset conv: 18 channels for both pixels -> 486 pk-FMA per pair.
    vf2 off2[OFFC];
    #pragma unroll
    for (int o = 0; o < OFFC; ++o) {
        vf2 a = splat2(conv_b[o]);
        #pragma unroll
        for (int c = 0; c < CIN; ++c)
            #pragma unroll
            for (int i = 0; i < 3; ++i)
                #pragma unroll
                for (int j = 0; j < 3; ++j)
                    a = __builtin_elementwise_fma(splat2(conv_w[o * 27 + c * 9 + i * 3 + j]),
                                                  xp2[i][j][c], a);
        off2[o] = a;
    }

    vf2 acc0 = splat2(dcn_b[0]);
    vf2 acc1 = splat2(dcn_b[1]);
    vf2 acc2 = splat2(dcn_b[2]);

    #pragma unroll
    for (int k = 0; k < KTAPS; ++k) {
        const int ky = k / 3;
        const int kx = k % 3;
        const vf2 oy = off2[2 * k];
        const vf2 ox = off2[2 * k + 1];
        const vf2 fy = __builtin_elementwise_floor(oy);
        const vf2 fx = __builtin_elementwise_floor(ox);
        const vf2 wy = oy - fy;
        const vf2 wx = ox - fx;

        // Packed bilinear weights (pk muls).
        const vf2 cwy = splat2(1.f) - wy;
        const vf2 cwx = splat2(1.f) - wx;
        const vf2 w00 = cwy * cwx;
        const vf2 w01 = cwy * wx;
        const vf2 w10 = wy * cwx;
        const vf2 w11 = wy * wx;

        // Corner coords per pixel (px1 is one column right).
        int iy0 = (int)fy.x + (ho + ky + PAD);
        int ix0 = (int)fx.x + (wo + kx + PAD);
        int iy1 = (int)fy.y + (ho + ky + PAD);
        int ix1 = (int)fx.y + (wo + 1 + kx + PAD);
        iy0 = min(max(iy0, 0), HP - 2);
        ix0 = min(max(ix0, 0), WP - 2);
        iy1 = min(max(iy1, 0), HP - 2);
        ix1 = min(max(ix1, 0), WP - 2);

        const float4* p0r0 = xtb + iy0 * WP + ix0;
        const float4* p0r1 = p0r0 + WP;
        const float4* p1r0 = xtb + iy1 * WP + ix1;
        const float4* p1r1 = p1r0 + WP;
        const float4 a00 = p0r0[0];
        const float4 a01 = p0r0[1];
        const float4 a10 = p0r1[0];
        const float4 a11 = p0r1[1];
        const float4 b00 = p1r0[0];
        const float4 b01 = p1r0[1];
        const float4 b10 = p1r1[0];
        const float4 b11 = p1r1[1];

        // Bilinear per channel for both pixels, packed: v pairs formed from
        // the two gathers, weights already packed.
        vf2 v00, v01, v10, v11, s0, s1, s2;
        v00.x = a00.x; v00.y = b00.x;
        v01.x = a01.x; v01.y = b01.x;
        v10.x = a10.x; v10.y = b10.x;
        v11.x = a11.x; v11.y = b11.x;
        s0 = v00 * w00;
        s0 = __builtin_elementwise_fma(v01, w01, s0);
        s0 = __builtin_elementwise_fma(v10, w10, s0);
        s0 = __builtin_elementwise_fma(v11, w11, s0);

        v00.x = a00.y; v00.y = b00.y;
        v01.x = a01.y; v01.y = b01.y;
        v10.x = a10.y; v10.y = b10.y;
        v11.x = a11.y; v11.y = b11.y;
        s1 = v00 * w00;
        s1 = __builtin_elementwise_fma(v01, w01, s1);
        s1 = __builtin_elementwise_fma(v10, w10, s1);
        s1 = __builtin_elementwise_fma(v11, w11, s1);

        v00.x = a00.z; v00.y = b00.z;
        v01.x = a01.z; v01.y = b01.z;
        v10.x = a10.z; v10.y = b10.z;
        v11.x = a11.z; v11.y = b11.z;
        s2 = v00 * w00;
        s2 = __builtin_elementwise_fma(v01, w01, s2);
        s2 = __builtin_elementwise_fma(v10, w10, s2);
        s2 = __builtin_elementwise_fma(v11, w11, s2);

        acc0 = __builtin_elementwise_fma(splat2(dcn_w[0 * 27 + 0 * 9 + k]), s0, acc0);
        acc0 = __builtin_elementwise_fma(splat2(dcn_w[0 * 27 + 1 * 9 + k]), s1, acc0);
        acc0 = __builtin_elementwise_fma(splat2(dcn_w[0 * 27 + 2 * 9 + k]), s2, acc0);
        acc1 = __builtin_elementwise_fma(splat2(dcn_w[1 * 27 + 0 * 9 + k]), s0, acc1);
        acc1 = __builtin_elementwise_fma(splat2(dcn_w[1 * 27 + 1 * 9 + k]), s1, acc1);
        acc1 = __builtin_elementwise_fma(splat2(dcn_w[1 * 27 + 2 * 9 + k]), s2, acc1);
        acc2 = __builtin_elementwise_fma(splat2(dcn_w[2 * 27 + 0 * 9 + k]), s0, acc2);
        acc2 = __builtin_elementwise_fma(splat2(dcn_w[2 * 27 + 1 * 9 + k]), s1, acc2);
        acc2 = __builtin_elementwise_fma(splat2(dcn_w[2 * 27 + 2 * 9 + k]), s2, acc2);
    }

    const int obase = b * (OOUT * HO * WO) + ho * WO + wo;
    __builtin_nontemporal_store(acc0, (vf2*)(out + obase));
    __builtin_nontemporal_store(acc1, (vf2*)(out + obase + HO * WO));
    __builtin_nontemporal_store(acc2, (vf2*)(out + obase + 2 * HO * WO));
}

// ---------------------------------------------------------------------------
// Fallback A (ws >= 28.3 MB): round-7 HWC float3 path (~88 us kernel).
__global__ __launch_bounds__(256)
void chw_to_hwc_kernel(const float* __restrict__ x, float* __restrict__ xt)
{
    const int gid = blockIdx.x * 256 + threadIdx.x;
    if (gid >= BATCH * HW) return;
    const int b = gid / HW;
    const int p = gid - b * HW;
    const float* xb = x + (size_t)b * (CIN * HW);
    F3 v;
    v.a = xb[p];
    v.b = xb[HW + p];
    v.c = xb[2 * HW + p];
    *(F3*)(xt + (size_t)gid * 3) = v;
}

__global__ __launch_bounds__(256)
void deform_hwc_kernel(const float* __restrict__ xt,
                       const float* __restrict__ conv_w,
                       const float* __restrict__ conv_b,
                       const float* __restrict__ dcn_w,
                       const float* __restrict__ dcn_b,
                       float* __restrict__ out)
{
    const int total = BATCH * HO * WO;
    const int gid = blockIdx.x * 256 + threadIdx.x;
    if (gid >= total) return;

    const int wo  = gid % WO;
    const int tmp = gid / WO;
    const int ho  = tmp % HO;
    const int b   = tmp / HO;

    const float* xtb = xt + (size_t)b * (HW * 3);

    F3 xp[3][3];
    #pragma unroll
    for (int i = 0; i < 3; ++i)
        #pragma unroll
        for (int j = 0; j < 3; ++j)
            xp[i][j] = *(const F3*)(xtb + (size_t)((ho + i) * W + (wo + j)) * 3);

    float off[OFFC];
    #pragma unroll
    for (int o = 0; o < OFFC; ++o) {
        float a = conv_b[o];
        #pragma unroll
        for (int i = 0; i < 3; ++i)
            #pragma unroll
            for (int j = 0; j < 3; ++j) {
                a = fmaf(conv_w[o * 27 + 0 * 9 + i * 3 + j], xp[i][j].a, a);
                a = fmaf(conv_w[o * 27 + 1 * 9 + i * 3 + j], xp[i][j].b, a);
                a = fmaf(conv_w[o * 27 + 2 * 9 + i * 3 + j], xp[i][j].c, a);
            }
        off[o] = a;
    }

    float acc0 = dcn_b[0];
    float acc1 = dcn_b[1];
    float acc2 = dcn_b[2];

    #pragma unroll
    for (int k = 0; k < KTAPS; ++k) {
        const int ky = k / 3;
        const int kx = k % 3;
        const float py = off[2 * k]     + (float)(ho + ky);
        const float px = off[2 * k + 1] + (float)(wo + kx);
        const float y0f = floorf(py);
        const float x0f = floorf(px);
        const float wy = py - y0f;
        const float wx = px - x0f;
        const int y0 = (int)y0f;
        const int x0 = (int)x0f;
        const int y1 = y0 + 1;
        const int x1 = x0 + 1;
        const bool vy0 = (unsigned)y0 < (unsigned)H;
        const bool vy1 = (unsigned)y1 < (unsigned)H;
        const bool vx0 = (unsigned)x0 < (unsigned)W;
        const bool vx1 = (unsigned)x1 < (unsigned)W;
        const int cy0 = min(max(y0, 0), H - 1);
        const int cy1 = min(max(y1, 0), H - 1);
        const int cx0 = min(max(x0, 0), W - 1);
        const int cx1 = min(max(x1, 0), W - 1);
        const float w00 = (vy0 && vx0) ? (1.f - wy) * (1.f - wx) : 0.f;
        const float w01 = (vy0 && vx1) ? (1.f - wy) * wx         : 0.f;
        const float w10 = (vy1 && vx0) ? wy * (1.f - wx)         : 0.f;
        const float w11 = (vy1 && vx1) ? wy * wx                 : 0.f;

        const F3 v00 = *(const F3*)(xtb + (size_t)(cy0 * W + cx0) * 3);
        const F3 v01 = *(const F3*)(xtb + (size_t)(cy0 * W + cx1) * 3);
        const F3 v10 = *(const F3*)(xtb + (size_t)(cy1 * W + cx0) * 3);
        const F3 v11 = *(const F3*)(xtb + (size_t)(cy1 * W + cx1) * 3);

        float s0 = v00.a * w00; s0 = fmaf(v01.a, w01, s0); s0 = fmaf(v10.a, w10, s0); s0 = fmaf(v11.a, w11, s0);
        float s1 = v00.b * w00; s1 = fmaf(v01.b, w01, s1); s1 = fmaf(v10.b, w10, s1); s1 = fmaf(v11.b, w11, s1);
        float s2 = v00.c * w00; s2 = fmaf(v01.c, w01, s2); s2 = fmaf(v10.c, w10, s2); s2 = fmaf(v11.c, w11, s2);

        acc0 = fmaf(dcn_w[0 * 27 + 0 * 9 + k], s0, acc0);
        acc0 = fmaf(dcn_w[0 * 27 + 1 * 9 + k], s1, acc0);
        acc0 = fmaf(dcn_w[0 * 27 + 2 * 9 + k], s2, acc0);
        acc1 = fmaf(dcn_w[1 * 27 + 0 * 9 + k], s0, acc1);
        acc1 = fmaf(dcn_w[1 * 27 + 1 * 9 + k], s1, acc1);
        acc1 = fmaf(dcn_w[1 * 27 + 2 * 9 + k], s2, acc1);
        acc2 = fmaf(dcn_w[2 * 27 + 0 * 9 + k], s0, acc2);
        acc2 = fmaf(dcn_w[2 * 27 + 1 * 9 + k], s1, acc2);
        acc2 = fmaf(dcn_w[2 * 27 + 2 * 9 + k], s2, acc2);
    }

    const int obase = b * (OOUT * HO * WO) + ho * WO + wo;
    __builtin_nontemporal_store(acc0, out + obase);
    __builtin_nontemporal_store(acc1, out + obase + HO * WO);
    __builtin_nontemporal_store(acc2, out + obase + 2 * HO * WO);
}

// ---------------------------------------------------------------------------
// Fallback B (tiny ws): round-2 fused kernel (~176 us), no workspace.
__global__ __launch_bounds__(256)
void deform_fused_kernel(const float* __restrict__ x,
                         const float* __restrict__ conv_w,
                         const float* __restrict__ conv_b,
                         const float* __restrict__ dcn_w,
                         const float* __restrict__ dcn_b,
                         float* __restrict__ out)
{
    __shared__ float s_cw[OFFC * 27];
    __shared__ float s_cb[OFFC];
    __shared__ float s_dw[OOUT * 27];
    __shared__ float s_db[OOUT];

    const int t = threadIdx.x;
    for (int i = t; i < OFFC * 27; i += 256) s_cw[i] = conv_w[i];
    if (t < OFFC)      s_cb[t] = conv_b[t];
    if (t < OOUT * 27) s_dw[t] = dcn_w[t];
    if (t < OOUT)      s_db[t] = dcn_b[t];
    __syncthreads();

    const int total = BATCH * HO * WO;
    const int gid = blockIdx.x * 256 + t;
    if (gid >= total) return;

    const int wo  = gid % WO;
    const int tmp = gid / WO;
    const int ho  = tmp % HO;
    const int b   = tmp / HO;

    const float* xb = x + b * (CIN * HW);

    float xp[CIN][3][3];
    #pragma unroll
    for (int c = 0; c < CIN; ++c) {
        const float* xc = xb + c * HW + ho * W + wo;
        #pragma unroll
        for (int i = 0; i < 3; ++i)
            #pragma unroll
            for (int j = 0; j < 3; ++j)
                xp[c][i][j] = xc[i * W + j];
    }

    float off[OFFC];
    #pragma unroll
    for (int o = 0; o < OFFC; ++o) {
        float a = s_cb[o];
        const float* wv = &s_cw[o * 27];
        #pragma unroll
        for (int c = 0; c < CIN; ++c)
            #pragma unroll
            for (int i = 0; i < 3; ++i)
                #pragma unroll
                for (int j = 0; j < 3; ++j)
                    a = fmaf(wv[c * 9 + i * 3 + j], xp[c][i][j], a);
        off[o] = a;
    }

    float a0 = s_db[0], a1 = s_db[1], a2 = s_db[2];

    #pragma unroll
    for (int k = 0; k < KTAPS; ++k) {
        const int ky = k / 3;
        const int kx = k % 3;
        const float py = off[2 * k]     + (float)(ho + ky);
        const float px = off[2 * k + 1] + (float)(wo + kx);
        const float y0f = floorf(py);
        const float x0f = floorf(px);
        const float wy = py - y0f;
        const float wx = px - x0f;
        const int y0 = (int)y0f;
        const int x0 = (int)x0f;
        const int y1 = y0 + 1;
        const int x1 = x0 + 1;
        const bool vy0 = (unsigned)y0 < (unsigned)H;
        const bool vy1 = (unsigned)y1 < (unsigned)H;
        const bool vx0 = (unsigned)x0 < (unsigned)W;
        const bool vx1 = (unsigned)x1 < (unsigned)W;
        const int cy0 = min(max(y0, 0), H - 1);
        const int cy1 = min(max(y1, 0), H - 1);
        const int cx0 = min(max(x0, 0), W - 1);
        const int cx1 = min(max(x1, 0), W - 1);
        const float w00 = (vy0 && vx0) ? (1.f - wy) * (1.f - wx) : 0.f;
        const float w01 = (vy0 && vx1) ? (1.f - wy) * wx         : 0.f;
        const float w10 = (vy1 && vx0) ? wy * (1.f - wx)         : 0.f;
        const float w11 = (vy1 && vx1) ? wy * wx                 : 0.f;
        const int i00 = cy0 * W + cx0;
        const int i01 = cy0 * W + cx1;
        const int i10 = cy1 * W + cx0;
        const int i11 = cy1 * W + cx1;
        #pragma unroll
        for (int c = 0; c < CIN; ++c) {
            const float* xc = xb + c * HW;
            float s = xc[i00] * w00;
            s = fmaf(xc[i01], w01, s);
            s = fmaf(xc[i10], w10, s);
            s = fmaf(xc[i11], w11, s);
            a0 = fmaf(s_dw[0 * 27 + c * 9 + k], s, a0);
            a1 = fmaf(s_dw[1 * 27 + c * 9 + k], s, a1);
            a2 = fmaf(s_dw[2 * 27 + c * 9 + k], s, a2);
        }
    }

    const int obase = b * (OOUT * HO * WO) + ho * WO + wo;
    __builtin_nontemporal_store(a0, out + obase);
    __builtin_nontemporal_store(a1, out + obase + HO * WO);
    __builtin_nontemporal_store(a2, out + obase + 2 * HO * WO);
}

extern "C" void kernel_launch(void* const* d_in, const int* in_sizes, int n_in,
                              void* d_out, int out_size, void* d_ws, size_t ws_size,
                              hipStream_t stream) {
    const float* x      = (const float*)d_in[0];
    const float* conv_w = (const float*)d_in[1];
    const float* conv_b = (const float*)d_in[2];
    const float* dcn_w  = (const float*)d_in[3];
    const float* dcn_b  = (const float*)d_in[4];
    float* out = (float*)d_out;

    const int total = BATCH * HO * WO;
    const size_t need4 = (size_t)BATCH * HP * WP * sizeof(float4);   // 38.5 MB
    const size_t need3 = (size_t)BATCH * HW * 3 * sizeof(float);     // 28.3 MB

    if (ws_size >= need4) {
        float4* xt = (float4*)d_ws;
        const int cells = BATCH * HP * WP;
        chw_to_hwc4_kernel<<<(cells + 255) / 256, 256, 0, stream>>>(x, xt);
        const int pairs = BATCH * HO * WO2;
        deform_pair_kernel<<<(pairs + 255) / 256, 256, 0, stream>>>(
            xt, conv_w, conv_b, dcn_w, dcn_b, out);
    } else if (ws_size >= need3) {
        float* xt = (float*)d_ws;
        chw_to_hwc_kernel<<<(BATCH * HW + 255) / 256, 256, 0, stream>>>(x, xt);
        deform_hwc_kernel<<<(total + 255) / 256, 256, 0, stream>>>(
            xt, conv_w, conv_b, dcn_w, dcn_b, out);
    } else {
        deform_fused_kernel<<<(total + 255) / 256, 256, 0, stream>>>(
            x, conv_w, conv_b, dcn_w, dcn_b, out);
    }
}

// Round 10
// 162.617 us; speedup vs baseline: 1.0219x; 1.0219x over previous
//
#include <hip/hip_runtime.h>

// Problem constants (from reference setup_inputs)
#define BATCH 16
#define CIN   3
#define H     384
#define W     384
#define HW    (H * W)
#define HO    382
#define WO    382
#define OFFC  18
#define OOUT  3
#define KTAPS 9

// Padded HWC-float4 layout: 2-px zero halo reproduces OOB-mask semantics.
#define PAD   2
#define HP    (H + 2 * PAD)     // 388
#define WP    (W + 2 * PAD)     // 388

// Packed-weight region (floats), appended to xt in workspace:
//  [0..485]   pk_cw : k in 0..8, idx in 0..26 -> {cw[2k][idx], cw[2k+1][idx]}
//  [486..503] pk_cb : {conv_b[2k], conv_b[2k+1]} (already contiguous)
//  [504..557] pk_dw : ck in 0..26 -> {dcn_w[0][ck], dcn_w[1][ck]}
//  [558..584] dw2   : dcn_w[2][ck]
//  [585..586] db01, [587] db2
#define WPK_FLOATS 588

typedef float vf2 __attribute__((ext_vector_type(2)));
struct F3 { float a, b, c; };

static __device__ __forceinline__ vf2 splat2(float s) { vf2 r; r.x = s; r.y = s; return r; }

// ---------------------------------------------------------------------------
// Pass 0: pack weights into pk layout (tiny; runs every call — graph-safe).
__global__ __launch_bounds__(256)
void prep_weights_kernel(const float* __restrict__ conv_w,
                         const float* __restrict__ conv_b,
                         const float* __restrict__ dcn_w,
                         const float* __restrict__ dcn_b,
                         float* __restrict__ wpk)
{
    for (int i = threadIdx.x; i < WPK_FLOATS; i += 256) {
        float v;
        if (i < 486) {
            const int k    = i / 54;
            const int r    = i - k * 54;
            const int idx  = r >> 1;
            const int half = r & 1;
            v = conv_w[(2 * k + half) * 27 + idx];
        } else if (i < 504) {
            v = conv_b[i - 486];
        } else if (i < 558) {
            const int r    = i - 504;
            const int ck   = r >> 1;
            const int half = r & 1;
            v = dcn_w[half * 27 + ck];
        } else if (i < 585) {
            v = dcn_w[2 * 27 + (i - 558)];
        } else if (i < 587) {
            v = dcn_b[i - 585];
        } else {
            v = dcn_b[2];
        }
        wpk[i] = v;
    }
}

// ---------------------------------------------------------------------------
// Pass 1: CHW -> padded HWC float4 (zero halo), 38.5 MB workspace.
__global__ __launch_bounds__(256)
void chw_to_hwc4_kernel(const float* __restrict__ x, float4* __restrict__ xt)
{
    const int gid = blockIdx.x * 256 + threadIdx.x;
    if (gid >= BATCH * HP * WP) return;
    const int b  = gid / (HP * WP);
    const int r2 = gid - b * (HP * WP);
    const int ry = r2 / WP;
    const int rx = r2 - ry * WP;
    const int yi = ry - PAD;
    const int xi = rx - PAD;
    float4 v = make_float4(0.f, 0.f, 0.f, 0.f);
    if ((unsigned)yi < (unsigned)H && (unsigned)xi < (unsigned)W) {
        const float* xb = x + (size_t)b * (CIN * HW);
        const int p = yi * W + xi;
        v.x = xb[p];
        v.y = xb[HW + p];
        v.z = xb[2 * HW + p];
    }
    xt[gid] = v;
}

// ---------------------------------------------------------------------------
// Pass 2: 1 px/thread (R8 shape) + intra-pixel vf2 packing:
//  - offset conv packs (dy,dx) channel pairs: 243 v_pk_fma_f32
//  - bilinear packs channels (0,1); accumulate packs outputs (0,1)
//  - tap coord math packs as (y,x)
// No masks (halo zeros), per-tap immediate consumption, scalar-cache weights.
__global__ __launch_bounds__(256)
void deform_pk_kernel(const float4* __restrict__ xt,
                      const float* __restrict__ wpk,
                      float* __restrict__ out)
{
    const int total = BATCH * HO * WO;
    const int gid = blockIdx.x * 256 + threadIdx.x;
    if (gid >= total) return;

    const int wo  = gid % WO;
    const int tmp = gid / WO;
    const int ho  = tmp % HO;
    const int b   = tmp / HO;

    const vf2*   pk_cw = (const vf2*)wpk;            // [k*27 + ck]
    const vf2*   pk_cb = (const vf2*)(wpk + 486);    // [k]
    const vf2*   pk_dw = (const vf2*)(wpk + 504);    // [c*9 + k]
    const float* dw2   = wpk + 558;                  // [c*9 + k]

    const float4* xtb = xt + (size_t)b * (HP * WP);

    // 3x3 patch (interior of padded frame).
    float4 xp[3][3];
    #pragma unroll
    for (int i = 0; i < 3; ++i) {
        const float4* row = xtb + (ho + i + PAD) * WP + (wo + PAD);
        xp[i][0] = row[0];
        xp[i][1] = row[1];
        xp[i][2] = row[2];
    }

    // Offset conv: 9 (dy,dx) pairs, 27 pk-FMA each.
    vf2 off2[KTAPS];
    #pragma unroll
    for (int k = 0; k < KTAPS; ++k) {
        vf2 a = pk_cb[k];
        #pragma unroll
        for (int i = 0; i < 3; ++i)
            #pragma unroll
            for (int j = 0; j < 3; ++j) {
                a = __builtin_elementwise_fma(pk_cw[k * 27 + 0 * 9 + i * 3 + j], splat2(xp[i][j].x), a);
                a = __builtin_elementwise_fma(pk_cw[k * 27 + 1 * 9 + i * 3 + j], splat2(xp[i][j].y), a);
                a = __builtin_elementwise_fma(pk_cw[k * 27 + 2 * 9 + i * 3 + j], splat2(xp[i][j].z), a);
            }
        off2[k] = a;
    }

    vf2   acc01 = *(const vf2*)(wpk + 585);
    float acc2  = wpk[587];

    #pragma unroll
    for (int k = 0; k < KTAPS; ++k) {
        const int ky = k / 3;
        const int kx = k % 3;
        const vf2 o = off2[k];               // (dy, dx)
        vf2 f;
        f.x = floorf(o.x);
        f.y = floorf(o.y);
        const vf2 w  = o - f;                // (wy, wx)
        const vf2 cw = splat2(1.f) - w;      // (cwy, cwx)

        int iy = (int)f.x + (ho + ky + PAD);
        int ix = (int)f.y + (wo + kx + PAD);
        iy = min(max(iy, 0), HP - 2);
        ix = min(max(ix, 0), WP - 2);

        const float4* r0 = xtb + iy * WP + ix;
        const float4* r1 = r0 + WP;
        const float4 v00 = r0[0];
        const float4 v01 = r0[1];
        const float4 v10 = r1[0];
        const float4 v11 = r1[1];

        const float w00 = cw.x * cw.y;
        const float w01 = cw.x * w.y;
        const float w10 = w.x * cw.y;
        const float w11 = w.x * w.y;

        // Channels 0,1 packed (low half of each float4).
        vf2 c00, c01, c10, c11;
        c00.x = v00.x; c00.y = v00.y;
        c01.x = v01.x; c01.y = v01.y;
        c10.x = v10.x; c10.y = v10.y;
        c11.x = v11.x; c11.y = v11.y;
        vf2 s01 = c00 * splat2(w00);
        s01 = __builtin_elementwise_fma(c01, splat2(w01), s01);
        s01 = __builtin_elementwise_fma(c10, splat2(w10), s01);
        s01 = __builtin_elementwise_fma(c11, splat2(w11), s01);

        float s2 = v00.z * w00;
        s2 = fmaf(v01.z, w01, s2);
        s2 = fmaf(v10.z, w10, s2);
        s2 = fmaf(v11.z, w11, s2);

        // Outputs (0,1) packed; output 2 scalar.
        acc01 = __builtin_elementwise_fma(pk_dw[0 * 9 + k], splat2(s01.x), acc01);
        acc01 = __builtin_elementwise_fma(pk_dw[1 * 9 + k], splat2(s01.y), acc01);
        acc01 = __builtin_elementwise_fma(pk_dw[2 * 9 + k], splat2(s2),    acc01);
        acc2 = fmaf(dw2[0 * 9 + k], s01.x, acc2);
        acc2 = fmaf(dw2[1 * 9 + k], s01.y, acc2);
        acc2 = fmaf(dw2[2 * 9 + k], s2,    acc2);
    }

    const int obase = b * (OOUT * HO * WO) + ho * WO + wo;
    __builtin_nontemporal_store(acc01.x, out + obase);
    __builtin_nontemporal_store(acc01.y, out + obase + HO * WO);
    __builtin_nontemporal_store(acc2,    out + obase + 2 * HO * WO);
}

// ---------------------------------------------------------------------------
// Fallback A (ws >= 28.3 MB): round-7 HWC float3 path (~88 us kernel).
__global__ __launch_bounds__(256)
void chw_to_hwc_kernel(const float* __restrict__ x, float* __restrict__ xt)
{
    const int gid = blockIdx.x * 256 + threadIdx.x;
    if (gid >= BATCH * HW) return;
    const int b = gid / HW;
    const int p = gid - b * HW;
    const float* xb = x + (size_t)b * (CIN * HW);
    F3 v;
    v.a = xb[p];
    v.b = xb[HW + p];
    v.c = xb[2 * HW + p];
    *(F3*)(xt + (size_t)gid * 3) = v;
}

__global__ __launch_bounds__(256)
void deform_hwc_kernel(const float* __restrict__ xt,
                       const float* __restrict__ conv_w,
                       const float* __restrict__ conv_b,
                       const float* __restrict__ dcn_w,
                       const float* __restrict__ dcn_b,
                       float* __restrict__ out)
{
    const int total = BATCH * HO * WO;
    const int gid = blockIdx.x * 256 + threadIdx.x;
    if (gid >= total) return;

    const int wo  = gid % WO;
    const int tmp = gid / WO;
    const int ho  = tmp % HO;
    const int b   = tmp / HO;

    const float* xtb = xt + (size_t)b * (HW * 3);

    F3 xp[3][3];
    #pragma unroll
    for (int i = 0; i < 3; ++i)
        #pragma unroll
        for (int j = 0; j < 3; ++j)
            xp[i][j] = *(const F3*)(xtb + (size_t)((ho + i) * W + (wo + j)) * 3);

    float off[OFFC];
    #pragma unroll
    for (int o = 0; o < OFFC; ++o) {
        float a = conv_b[o];
        #pragma unroll
        for (int i = 0; i < 3; ++i)
            #pragma unroll
            for (int j = 0; j < 3; ++j) {
                a = fmaf(conv_w[o * 27 + 0 * 9 + i * 3 + j], xp[i][j].a, a);
                a = fmaf(conv_w[o * 27 + 1 * 9 + i * 3 + j], xp[i][j].b, a);
                a = fmaf(conv_w[o * 27 + 2 * 9 + i * 3 + j], xp[i][j].c, a);
            }
        off[o] = a;
    }

    float acc0 = dcn_b[0];
    float acc1 = dcn_b[1];
    float acc2 = dcn_b[2];

    #pragma unroll
    for (int k = 0; k < KTAPS; ++k) {
        const int ky = k / 3;
        const int kx = k % 3;
        const float py = off[2 * k]     + (float)(ho + ky);
        const float px = off[2 * k + 1] + (float)(wo + kx);
        const float y0f = floorf(py);
        const float x0f = floorf(px);
        const float wy = py - y0f;
        const float wx = px - x0f;
        const int y0 = (int)y0f;
        const int x0 = (int)x0f;
        const int y1 = y0 + 1;
        const int x1 = x0 + 1;
        const bool vy0 = (unsigned)y0 < (unsigned)H;
        const bool vy1 = (unsigned)y1 < (unsigned)H;
        const bool vx0 = (unsigned)x0 < (unsigned)W;
        const bool vx1 = (unsigned)x1 < (unsigned)W;
        const int cy0 = min(max(y0, 0), H - 1);
        const int cy1 = min(max(y1, 0), H - 1);
        const int cx0 = min(max(x0, 0), W - 1);
        const int cx1 = min(max(x1, 0), W - 1);
        const float w00 = (vy0 && vx0) ? (1.f - wy) * (1.f - wx) : 0.f;
        const float w01 = (vy0 && vx1) ? (1.f - wy) * wx         : 0.f;
        const float w10 = (vy1 && vx0) ? wy * (1.f - wx)         : 0.f;
        const float w11 = (vy1 && vx1) ? wy * wx                 : 0.f;

        const F3 v00 = *(const F3*)(xtb + (size_t)(cy0 * W + cx0) * 3);
        const F3 v01 = *(const F3*)(xtb + (size_t)(cy0 * W + cx1) * 3);
        const F3 v10 = *(const F3*)(xtb + (size_t)(cy1 * W + cx0) * 3);
        const F3 v11 = *(const F3*)(xtb + (size_t)(cy1 * W + cx1) * 3);

        float s0 = v00.a * w00; s0 = fmaf(v01.a, w01, s0); s0 = fmaf(v10.a, w10, s0); s0 = fmaf(v11.a, w11, s0);
        float s1 = v00.b * w00; s1 = fmaf(v01.b, w01, s1); s1 = fmaf(v10.b, w10, s1); s1 = fmaf(v11.b, w11, s1);
        float s2 = v00.c * w00; s2 = fmaf(v01.c, w01, s2); s2 = fmaf(v10.c, w10, s2); s2 = fmaf(v11.c, w11, s2);

        acc0 = fmaf(dcn_w[0 * 27 + 0 * 9 + k], s0, acc0);
        acc0 = fmaf(dcn_w[0 * 27 + 1 * 9 + k], s1, acc0);
        acc0 = fmaf(dcn_w[0 * 27 + 2 * 9 + k], s2, acc0);
        acc1 = fmaf(dcn_w[1 * 27 + 0 * 9 + k], s0, acc1);
        acc1 = fmaf(dcn_w[1 * 27 + 1 * 9 + k], s1, acc1);
        acc1 = fmaf(dcn_w[1 * 27 + 2 * 9 + k], s2, acc1);
        acc2 = fmaf(dcn_w[2 * 27 + 0 * 9 + k], s0, acc2);
        acc2 = fmaf(dcn_w[2 * 27 + 1 * 9 + k], s1, acc2);
        acc2 = fmaf(dcn_w[2 * 27 + 2 * 9 + k], s2, acc2);
    }

    const int obase = b * (OOUT * HO * WO) + ho * WO + wo;
    __builtin_nontemporal_store(acc0, out + obase);
    __builtin_nontemporal_store(acc1, out + obase + HO * WO);
    __builtin_nontemporal_store(acc2, out + obase + 2 * HO * WO);
}

// ---------------------------------------------------------------------------
// Fallback B (tiny ws): round-2 fused kernel (~176 us), no workspace.
__global__ __launch_bounds__(256)
void deform_fused_kernel(const float* __restrict__ x,
                         const float* __restrict__ conv_w,
                         const float* __restrict__ conv_b,
                         const float* __restrict__ dcn_w,
                         const float* __restrict__ dcn_b,
                         float* __restrict__ out)
{
    __shared__ float s_cw[OFFC * 27];
    __shared__ float s_cb[OFFC];
    __shared__ float s_dw[OOUT * 27];
    __shared__ float s_db[OOUT];

    const int t = threadIdx.x;
    for (int i = t; i < OFFC * 27; i += 256) s_cw[i] = conv_w[i];
    if (t < OFFC)      s_cb[t] = conv_b[t];
    if (t < OOUT * 27) s_dw[t] = dcn_w[t];
    if (t < OOUT)      s_db[t] = dcn_b[t];
    __syncthreads();

    const int total = BATCH * HO * WO;
    const int gid = blockIdx.x * 256 + t;
    if (gid >= total) return;

    const int wo  = gid % WO;
    const int tmp = gid / WO;
    const int ho  = tmp % HO;
    const int b   = tmp / HO;

    const float* xb = x + b * (CIN * HW);

    float xp[CIN][3][3];
    #pragma unroll
    for (int c = 0; c < CIN; ++c) {
        const float* xc = xb + c * HW + ho * W + wo;
        #pragma unroll
        for (int i = 0; i < 3; ++i)
            #pragma unroll
            for (int j = 0; j < 3; ++j)
                xp[c][i][j] = xc[i * W + j];
    }

    float off[OFFC];
    #pragma unroll
    for (int o = 0; o < OFFC; ++o) {
        float a = s_cb[o];
        const float* wv = &s_cw[o * 27];
        #pragma unroll
        for (int c = 0; c < CIN; ++c)
            #pragma unroll
            for (int i = 0; i < 3; ++i)
                #pragma unroll
                for (int j = 0; j < 3; ++j)
                    a = fmaf(wv[c * 9 + i * 3 + j], xp[c][i][j], a);
        off[o] = a;
    }

    float a0 = s_db[0], a1 = s_db[1], a2 = s_db[2];

    #pragma unroll
    for (int k = 0; k < KTAPS; ++k) {
        const int ky = k / 3;
        const int kx = k % 3;
        const float py = off[2 * k]     + (float)(ho + ky);
        const float px = off[2 * k + 1] + (float)(wo + kx);
        const float y0f = floorf(py);
        const float x0f = floorf(px);
        const float wy = py - y0f;
        const float wx = px - x0f;
        const int y0 = (int)y0f;
        const int x0 = (int)x0f;
        const int y1 = y0 + 1;
        const int x1 = x0 + 1;
        const bool vy0 = (unsigned)y0 < (unsigned)H;
        const bool vy1 = (unsigned)y1 < (unsigned)H;
        const bool vx0 = (unsigned)x0 < (unsigned)W;
        const bool vx1 = (unsigned)x1 < (unsigned)W;
        const int cy0 = min(max(y0, 0), H - 1);
        const int cy1 = min(max(y1, 0), H - 1);
        const int cx0 = min(max(x0, 0), W - 1);
        const int cx1 = min(max(x1, 0), W - 1);
        const float w00 = (vy0 && vx0) ? (1.f - wy) * (1.f - wx) : 0.f;
        const float w01 = (vy0 && vx1) ? (1.f - wy) * wx         : 0.f;
        const float w10 = (vy1 && vx0) ? wy * (1.f - wx)         : 0.f;
        const float w11 = (vy1 && vx1) ? wy * wx                 : 0.f;
        const int i00 = cy0 * W + cx0;
        const int i01 = cy0 * W + cx1;
        const int i10 = cy1 * W + cx0;
        const int i11 = cy1 * W + cx1;
        #pragma unroll
        for (int c = 0; c < CIN; ++c) {
            const float* xc = xb + c * HW;
            float s = xc[i00] * w00;
            s = fmaf(xc[i01], w01, s);
            s = fmaf(xc[i10], w10, s);
            s = fmaf(xc[i11], w11, s);
            a0 = fmaf(s_dw[0 * 27 + c * 9 + k], s, a0);
            a1 = fmaf(s_dw[1 * 27 + c * 9 + k], s, a1);
            a2 = fmaf(s_dw[2 * 27 + c * 9 + k], s, a2);
        }
    }

    const int obase = b * (OOUT * HO * WO) + ho * WO + wo;
    __builtin_nontemporal_store(a0, out + obase);
    __builtin_nontemporal_store(a1, out + obase + HO * WO);
    __builtin_nontemporal_store(a2, out + obase + 2 * HO * WO);
}

extern "C" void kernel_launch(void* const* d_in, const int* in_sizes, int n_in,
                              void* d_out, int out_size, void* d_ws, size_t ws_size,
                              hipStream_t stream) {
    const float* x      = (const float*)d_in[0];
    const float* conv_w = (const float*)d_in[1];
    const float* conv_b = (const float*)d_in[2];
    const float* dcn_w  = (const float*)d_in[3];
    const float* dcn_b  = (const float*)d_in[4];
    float* out = (float*)d_out;

    const int total = BATCH * HO * WO;
    const size_t xt_bytes = (size_t)BATCH * HP * WP * sizeof(float4);   // 38.5 MB
    const size_t need4 = xt_bytes + WPK_FLOATS * sizeof(float);
    const size_t need3 = (size_t)BATCH * HW * 3 * sizeof(float);        // 28.3 MB

    if (ws_size >= need4) {
        float4* xt = (float4*)d_ws;
        float* wpk = (float*)((char*)d_ws + xt_bytes);
        prep_weights_kernel<<<1, 256, 0, stream>>>(conv_w, conv_b, dcn_w, dcn_b, wpk);
        const int cells = BATCH * HP * WP;
        chw_to_hwc4_kernel<<<(cells + 255) / 256, 256, 0, stream>>>(x, xt);
        deform_pk_kernel<<<(total + 255) / 256, 256, 0, stream>>>(xt, wpk, out);
    } else if (ws_size >= need3) {
        float* xt = (float*)d_ws;
        chw_to_hwc_kernel<<<(BATCH * HW + 255) / 256, 256, 0, stream>>>(x, xt);
        deform_hwc_kernel<<<(total + 255) / 256, 256, 0, stream>>>(
            xt, conv_w, conv_b, dcn_w, dcn_b, out);
    } else {
        deform_fused_kernel<<<(total + 255) / 256, 256, 0, stream>>>(
            x, conv_w, conv_b, dcn_w, dcn_b, out);
    }
}

// Round 11
// 147.141 us; speedup vs baseline: 1.1294x; 1.1052x over previous
//
#include <hip/hip_runtime.h>

// Problem constants (from reference setup_inputs)
#define BATCH 16
#define CIN   3
#define H     384
#define W     384
#define HW    (H * W)
#define HO    382
#define WO    382
#define OFFC  18
#define OOUT  3
#define KTAPS 9

// Padded HWC layout: 2-px zero halo reproduces OOB-mask semantics.
#define PAD   2
#define HP    (H + 2 * PAD)     // 388
#define WP    (W + 2 * PAD)     // 388

// Packed-weight region (floats):
//  [0..485]   pk_cw : k in 0..8, idx in 0..26 -> {cw[2k][idx], cw[2k+1][idx]}
//  [486..503] pk_cb : {conv_b[2k], conv_b[2k+1]}
//  [504..557] pk_dw : ck in 0..26 -> {dcn_w[0][ck], dcn_w[1][ck]}
//  [558..584] dw2   : dcn_w[2][ck]
//  [585..586] db01, [587] db2
#define WPK_FLOATS 588

typedef float vf2 __attribute__((ext_vector_type(2)));
struct F3 { float a, b, c; };

static __device__ __forceinline__ vf2 splat2(float s) { vf2 r; r.x = s; r.y = s; return r; }

// bf16 helpers: RNE pack, and cheap unpack (bf16<<16 IS the fp32).
static __device__ __forceinline__ unsigned f2bf(float f) {
    const unsigned u = __float_as_uint(f);
    return (u + 0x7fffu + ((u >> 16) & 1u)) >> 16;
}
static __device__ __forceinline__ float bf_lo(unsigned d) { return __uint_as_float(d << 16); }
static __device__ __forceinline__ float bf_hi(unsigned d) { return __uint_as_float(d & 0xffff0000u); }

// ---------------------------------------------------------------------------
// Pass 0: pack weights into pk layout (tiny; runs every call — graph-safe).
__global__ __launch_bounds__(256)
void prep_weights_kernel(const float* __restrict__ conv_w,
                         const float* __restrict__ conv_b,
                         const float* __restrict__ dcn_w,
                         const float* __restrict__ dcn_b,
                         float* __restrict__ wpk)
{
    for (int i = threadIdx.x; i < WPK_FLOATS; i += 256) {
        float v;
        if (i < 486) {
            const int k    = i / 54;
            const int r    = i - k * 54;
            const int idx  = r >> 1;
            const int half = r & 1;
            v = conv_w[(2 * k + half) * 27 + idx];
        } else if (i < 504) {
            v = conv_b[i - 486];
        } else if (i < 558) {
            const int r    = i - 504;
            const int ck   = r >> 1;
            const int half = r & 1;
            v = dcn_w[half * 27 + ck];
        } else if (i < 585) {
            v = dcn_w[2 * 27 + (i - 558)];
        } else if (i < 587) {
            v = dcn_b[i - 585];
        } else {
            v = dcn_b[2];
        }
        wpk[i] = v;
    }
}

// ---------------------------------------------------------------------------
// Pass 1: CHW fp32 -> padded HWC bf16x4 (8 B/px: d0 = ch0|ch1<<16, d1 = ch2).
// Zero halo. 19.3 MB workspace -> gather cacheline traffic halves vs fp32.
__global__ __launch_bounds__(256)
void chw_to_bf16hwc_kernel(const float* __restrict__ x, uint2* __restrict__ xt)
{
    const int gid = blockIdx.x * 256 + threadIdx.x;
    if (gid >= BATCH * HP * WP) return;
    const int b  = gid / (HP * WP);
    const int r2 = gid - b * (HP * WP);
    const int ry = r2 / WP;
    const int rx = r2 - ry * WP;
    const int yi = ry - PAD;
    const int xi = rx - PAD;
    uint2 v = make_uint2(0u, 0u);
    if ((unsigned)yi < (unsigned)H && (unsigned)xi < (unsigned)W) {
        const float* xb = x + (size_t)b * (CIN * HW);
        const int p = yi * W + xi;
        v.x = f2bf(xb[p]) | (f2bf(xb[HW + p]) << 16);
        v.y = f2bf(xb[2 * HW + p]);
    }
    xt[gid] = v;
}

// ---------------------------------------------------------------------------
// Pass 2: 1 px/thread. Offset conv from ORIGINAL fp32 x (dense coalesced
// loads -> sampling positions identical to the fp32 kernels). Gathers from
// bf16 HWC buffer (half the cacheline traffic). pk-packed math throughout.
__global__ __launch_bounds__(256)
void deform_bf16_kernel(const float* __restrict__ x,
                        const uint2* __restrict__ xt,
                        const float* __restrict__ wpk,
                        float* __restrict__ out)
{
    const int total = BATCH * HO * WO;
    const int gid = blockIdx.x * 256 + threadIdx.x;
    if (gid >= total) return;

    const int wo  = gid % WO;
    const int tmp = gid / WO;
    const int ho  = tmp % HO;
    const int b   = tmp / HO;

    const vf2*   pk_cw = (const vf2*)wpk;            // [k*27 + ck]
    const vf2*   pk_cb = (const vf2*)(wpk + 486);    // [k]
    const vf2*   pk_dw = (const vf2*)(wpk + 504);    // [c*9 + k]
    const float* dw2   = wpk + 558;                  // [c*9 + k]

    const float* xb  = x  + (size_t)b * (CIN * HW);
    const uint2* xtb = xt + (size_t)b * (HP * WP);

    // 3x3x3 fp32 patch from original CHW x (dense, 4 lines per wave-load).
    float xp[CIN][3][3];
    #pragma unroll
    for (int c = 0; c < CIN; ++c) {
        const float* xc = xb + c * HW + ho * W + wo;
        #pragma unroll
        for (int i = 0; i < 3; ++i)
            #pragma unroll
            for (int j = 0; j < 3; ++j)
                xp[c][i][j] = xc[i * W + j];
    }

    // Offset conv: 9 (dy,dx) pairs, 27 pk-FMA each (fp32-exact positions).
    vf2 off2[KTAPS];
    #pragma unroll
    for (int k = 0; k < KTAPS; ++k) {
        vf2 a = pk_cb[k];
        #pragma unroll
        for (int c = 0; c < CIN; ++c)
            #pragma unroll
            for (int i = 0; i < 3; ++i)
                #pragma unroll
                for (int j = 0; j < 3; ++j)
                    a = __builtin_elementwise_fma(pk_cw[k * 27 + c * 9 + i * 3 + j],
                                                  splat2(xp[c][i][j]), a);
        off2[k] = a;
    }

    vf2   acc01 = *(const vf2*)(wpk + 585);
    float acc2  = wpk[587];

    #pragma unroll
    for (int k = 0; k < KTAPS; ++k) {
        const int ky = k / 3;
        const int kx = k % 3;
        const vf2 o = off2[k];               // (dy, dx)
        vf2 f;
        f.x = floorf(o.x);
        f.y = floorf(o.y);
        const vf2 w  = o - f;                // (wy, wx)
        const vf2 cw = splat2(1.f) - w;      // (cwy, cwx)

        int iy = (int)f.x + (ho + ky + PAD);
        int ix = (int)f.y + (wo + kx + PAD);
        iy = min(max(iy, 0), HP - 2);
        ix = min(max(ix, 0), WP - 2);

        const uint2* base = xtb + iy * WP + ix;
        const uint2 q00 = base[0];
        const uint2 q01 = base[1];
        const uint2 q10 = base[WP];
        const uint2 q11 = base[WP + 1];

        const float w00 = cw.x * cw.y;
        const float w01 = cw.x * w.y;
        const float w10 = w.x * cw.y;
        const float w11 = w.x * w.y;

        // Channels (0,1) packed from d0; channel 2 from d1.
        vf2 c00, c01, c10, c11;
        c00.x = bf_lo(q00.x); c00.y = bf_hi(q00.x);
        c01.x = bf_lo(q01.x); c01.y = bf_hi(q01.x);
        c10.x = bf_lo(q10.x); c10.y = bf_hi(q10.x);
        c11.x = bf_lo(q11.x); c11.y = bf_hi(q11.x);
        vf2 s01 = c00 * splat2(w00);
        s01 = __builtin_elementwise_fma(c01, splat2(w01), s01);
        s01 = __builtin_elementwise_fma(c10, splat2(w10), s01);
        s01 = __builtin_elementwise_fma(c11, splat2(w11), s01);

        float s2 = bf_lo(q00.y) * w00;
        s2 = fmaf(bf_lo(q01.y), w01, s2);
        s2 = fmaf(bf_lo(q10.y), w10, s2);
        s2 = fmaf(bf_lo(q11.y), w11, s2);

        acc01 = __builtin_elementwise_fma(pk_dw[0 * 9 + k], splat2(s01.x), acc01);
        acc01 = __builtin_elementwise_fma(pk_dw[1 * 9 + k], splat2(s01.y), acc01);
        acc01 = __builtin_elementwise_fma(pk_dw[2 * 9 + k], splat2(s2),    acc01);
        acc2 = fmaf(dw2[0 * 9 + k], s01.x, acc2);
        acc2 = fmaf(dw2[1 * 9 + k], s01.y, acc2);
        acc2 = fmaf(dw2[2 * 9 + k], s2,    acc2);
    }

    const int obase = b * (OOUT * HO * WO) + ho * WO + wo;
    __builtin_nontemporal_store(acc01.x, out + obase);
    __builtin_nontemporal_store(acc01.y, out + obase + HO * WO);
    __builtin_nontemporal_store(acc2,    out + obase + 2 * HO * WO);
}

// ---------------------------------------------------------------------------
// Fallback A (ws >= 28.3 MB): round-7 HWC float3 path (~88 us kernel).
__global__ __launch_bounds__(256)
void chw_to_hwc_kernel(const float* __restrict__ x, float* __restrict__ xt)
{
    const int gid = blockIdx.x * 256 + threadIdx.x;
    if (gid >= BATCH * HW) return;
    const int b = gid / HW;
    const int p = gid - b * HW;
    const float* xb = x + (size_t)b * (CIN * HW);
    F3 v;
    v.a = xb[p];
    v.b = xb[HW + p];
    v.c = xb[2 * HW + p];
    *(F3*)(xt + (size_t)gid * 3) = v;
}

__global__ __launch_bounds__(256)
void deform_hwc_kernel(const float* __restrict__ xt,
                       const float* __restrict__ conv_w,
                       const float* __restrict__ conv_b,
                       const float* __restrict__ dcn_w,
                       const float* __restrict__ dcn_b,
                       float* __restrict__ out)
{
    const int total = BATCH * HO * WO;
    const int gid = blockIdx.x * 256 + threadIdx.x;
    if (gid >= total) return;

    const int wo  = gid % WO;
    const int tmp = gid / WO;
    const int ho  = tmp % HO;
    const int b   = tmp / HO;

    const float* xtb = xt + (size_t)b * (HW * 3);

    F3 xp[3][3];
    #pragma unroll
    for (int i = 0; i < 3; ++i)
        #pragma unroll
        for (int j = 0; j < 3; ++j)
            xp[i][j] = *(const F3*)(xtb + (size_t)((ho + i) * W + (wo + j)) * 3);

    float off[OFFC];
    #pragma unroll
    for (int o = 0; o < OFFC; ++o) {
        float a = conv_b[o];
        #pragma unroll
        for (int i = 0; i < 3; ++i)
            #pragma unroll
            for (int j = 0; j < 3; ++j) {
                a = fmaf(conv_w[o * 27 + 0 * 9 + i * 3 + j], xp[i][j].a, a);
                a = fmaf(conv_w[o * 27 + 1 * 9 + i * 3 + j], xp[i][j].b, a);
                a = fmaf(conv_w[o * 27 + 2 * 9 + i * 3 + j], xp[i][j].c, a);
            }
        off[o] = a;
    }

    float acc0 = dcn_b[0];
    float acc1 = dcn_b[1];
    float acc2 = dcn_b[2];

    #pragma unroll
    for (int k = 0; k < KTAPS; ++k) {
        const int ky = k / 3;
        const int kx = k % 3;
        const float py = off[2 * k]     + (float)(ho + ky);
        const float px = off[2 * k + 1] + (float)(wo + kx);
        const float y0f = floorf(py);
        const float x0f = floorf(px);
        const float wy = py - y0f;
        const float wx = px - x0f;
        const int y0 = (int)y0f;
        const int x0 = (int)x0f;
        const int y1 = y0 + 1;
        const int x1 = x0 + 1;
        const bool vy0 = (unsigned)y0 < (unsigned)H;
        const bool vy1 = (unsigned)y1 < (unsigned)H;
        const bool vx0 = (unsigned)x0 < (unsigned)W;
        const bool vx1 = (unsigned)x1 < (unsigned)W;
        const int cy0 = min(max(y0, 0), H - 1);
        const int cy1 = min(max(y1, 0), H - 1);
        const int cx0 = min(max(x0, 0), W - 1);
        const int cx1 = min(max(x1, 0), W - 1);
        const float w00 = (vy0 && vx0) ? (1.f - wy) * (1.f - wx) : 0.f;
        const float w01 = (vy0 && vx1) ? (1.f - wy) * wx         : 0.f;
        const float w10 = (vy1 && vx0) ? wy * (1.f - wx)         : 0.f;
        const float w11 = (vy1 && vx1) ? wy * wx                 : 0.f;

        const F3 v00 = *(const F3*)(xtb + (size_t)(cy0 * W + cx0) * 3);
        const F3 v01 = *(const F3*)(xtb + (size_t)(cy0 * W + cx1) * 3);
        const F3 v10 = *(const F3*)(xtb + (size_t)(cy1 * W + cx0) * 3);
        const F3 v11 = *(const F3*)(xtb + (size_t)(cy1 * W + cx1) * 3);

        float s0 = v00.a * w00; s0 = fmaf(v01.a, w01, s0); s0 = fmaf(v10.a, w10, s0); s0 = fmaf(v11.a, w11, s0);
        float s1 = v00.b * w00; s1 = fmaf(v01.b, w01, s1); s1 = fmaf(v10.b, w10, s1); s1 = fmaf(v11.b, w11, s1);
        float s2 = v00.c * w00; s2 = fmaf(v01.c, w01, s2); s2 = fmaf(v10.c, w10, s2); s2 = fmaf(v11.c, w11, s2);

        acc0 = fmaf(dcn_w[0 * 27 + 0 * 9 + k], s0, acc0);
        acc0 = fmaf(dcn_w[0 * 27 + 1 * 9 + k], s1, acc0);
        acc0 = fmaf(dcn_w[0 * 27 + 2 * 9 + k], s2, acc0);
        acc1 = fmaf(dcn_w[1 * 27 + 0 * 9 + k], s0, acc1);
        acc1 = fmaf(dcn_w[1 * 27 + 1 * 9 + k], s1, acc1);
        acc1 = fmaf(dcn_w[1 * 27 + 2 * 9 + k], s2, acc1);
        acc2 = fmaf(dcn_w[2 * 27 + 0 * 9 + k], s0, acc2);
        acc2 = fmaf(dcn_w[2 * 27 + 1 * 9 + k], s1, acc2);
        acc2 = fmaf(dcn_w[2 * 27 + 2 * 9 + k], s2, acc2);
    }

    const int obase = b * (OOUT * HO * WO) + ho * WO + wo;
    __builtin_nontemporal_store(acc0, out + obase);
    __builtin_nontemporal_store(acc1, out + obase + HO * WO);
    __builtin_nontemporal_store(acc2, out + obase + 2 * HO * WO);
}

// ---------------------------------------------------------------------------
// Fallback B (tiny ws): round-2 fused kernel (~176 us), no workspace.
__global__ __launch_bounds__(256)
void deform_fused_kernel(const float* __restrict__ x,
                         const float* __restrict__ conv_w,
                         const float* __restrict__ conv_b,
                         const float* __restrict__ dcn_w,
                         const float* __restrict__ dcn_b,
                         float* __restrict__ out)
{
    __shared__ float s_cw[OFFC * 27];
    __shared__ float s_cb[OFFC];
    __shared__ float s_dw[OOUT * 27];
    __shared__ float s_db[OOUT];

    const int t = threadIdx.x;
    for (int i = t; i < OFFC * 27; i += 256) s_cw[i] = conv_w[i];
    if (t < OFFC)      s_cb[t] = conv_b[t];
    if (t < OOUT * 27) s_dw[t] = dcn_w[t];
    if (t < OOUT)      s_db[t] = dcn_b[t];
    __syncthreads();

    const int total = BATCH * HO * WO;
    const int gid = blockIdx.x * 256 + t;
    if (gid >= total) return;

    const int wo  = gid % WO;
    const int tmp = gid / WO;
    const int ho  = tmp % HO;
    const int b   = tmp / HO;

    const float* xb = x + b * (CIN * HW);

    float xp[CIN][3][3];
    #pragma unroll
    for (int c = 0; c < CIN; ++c) {
        const float* xc = xb + c * HW + ho * W + wo;
        #pragma unroll
        for (int i = 0; i < 3; ++i)
            #pragma unroll
            for (int j = 0; j < 3; ++j)
                xp[c][i][j] = xc[i * W + j];
    }

    float off[OFFC];
    #pragma unroll
    for (int o = 0; o < OFFC; ++o) {
        float a = s_cb[o];
        const float* wv = &s_cw[o * 27];
        #pragma unroll
        for (int c = 0; c < CIN; ++c)
            #pragma unroll
            for (int i = 0; i < 3; ++i)
                #pragma unroll
                for (int j = 0; j < 3; ++j)
                    a = fmaf(wv[c * 9 + i * 3 + j], xp[c][i][j], a);
        off[o] = a;
    }

    float a0 = s_db[0], a1 = s_db[1], a2 = s_db[2];

    #pragma unroll
    for (int k = 0; k < KTAPS; ++k) {
        const int ky = k / 3;
        const int kx = k % 3;
        const float py = off[2 * k]     + (float)(ho + ky);
        const float px = off[2 * k + 1] + (float)(wo + kx);
        const float y0f = floorf(py);
        const float x0f = floorf(px);
        const float wy = py - y0f;
        const float wx = px - x0f;
        const int y0 = (int)y0f;
        const int x0 = (int)x0f;
        const int y1 = y0 + 1;
        const int x1 = x0 + 1;
        const bool vy0 = (unsigned)y0 < (unsigned)H;
        const bool vy1 = (unsigned)y1 < (unsigned)H;
        const bool vx0 = (unsigned)x0 < (unsigned)W;
        const bool vx1 = (unsigned)x1 < (unsigned)W;
        const int cy0 = min(max(y0, 0), H - 1);
        const int cy1 = min(max(y1, 0), H - 1);
        const int cx0 = min(max(x0, 0), W - 1);
        const int cx1 = min(max(x1, 0), W - 1);
        const float w00 = (vy0 && vx0) ? (1.f - wy) * (1.f - wx) : 0.f;
        const float w01 = (vy0 && vx1) ? (1.f - wy) * wx         : 0.f;
        const float w10 = (vy1 && vx0) ? wy * (1.f - wx)         : 0.f;
        const float w11 = (vy1 && vx1) ? wy * wx                 : 0.f;
        const int i00 = cy0 * W + cx0;
        const int i01 = cy0 * W + cx1;
        const int i10 = cy1 * W + cx0;
        const int i11 = cy1 * W + cx1;
        #pragma unroll
        for (int c = 0; c < CIN; ++c) {
            const float* xc = xb + c * HW;
            float s = xc[i00] * w00;
            s = fmaf(xc[i01], w01, s);
            s = fmaf(xc[i10], w10, s);
            s = fmaf(xc[i11], w11, s);
            a0 = fmaf(s_dw[0 * 27 + c * 9 + k], s, a0);
            a1 = fmaf(s_dw[1 * 27 + c * 9 + k], s, a1);
            a2 = fmaf(s_dw[2 * 27 + c * 9 + k], s, a2);
        }
    }

    const int obase = b * (OOUT * HO * WO) + ho * WO + wo;
    __builtin_nontemporal_store(a0, out + obase);
    __builtin_nontemporal_store(a1, out + obase + HO * WO);
    __builtin_nontemporal_store(a2, out + obase + 2 * HO * WO);
}

extern "C" void kernel_launch(void* const* d_in, const int* in_sizes, int n_in,
                              void* d_out, int out_size, void* d_ws, size_t ws_size,
                              hipStream_t stream) {
    const float* x      = (const float*)d_in[0];
    const float* conv_w = (const float*)d_in[1];
    const float* conv_b = (const float*)d_in[2];
    const float* dcn_w  = (const float*)d_in[3];
    const float* dcn_b  = (const float*)d_in[4];
    float* out = (float*)d_out;

    const int total = BATCH * HO * WO;
    const size_t xt_bytes = (size_t)BATCH * HP * WP * sizeof(uint2);   // 19.3 MB
    const size_t need_bf = xt_bytes + WPK_FLOATS * sizeof(float);
    const size_t need3   = (size_t)BATCH * HW * 3 * sizeof(float);     // 28.3 MB

    if (ws_size >= need_bf) {
        uint2* xt = (uint2*)d_ws;
        float* wpk = (float*)((char*)d_ws + xt_bytes);
        prep_weights_kernel<<<1, 256, 0, stream>>>(conv_w, conv_b, dcn_w, dcn_b, wpk);
        const int cells = BATCH * HP * WP;
        chw_to_bf16hwc_kernel<<<(cells + 255) / 256, 256, 0, stream>>>(x, xt);
        deform_bf16_kernel<<<(total + 255) / 256, 256, 0, stream>>>(x, xt, wpk, out);
    } else if (ws_size >= need3) {
        float* xt = (float*)d_ws;
        chw_to_hwc_kernel<<<(BATCH * HW + 255) / 256, 256, 0, stream>>>(x, xt);
        deform_hwc_kernel<<<(total + 255) / 256, 256, 0, stream>>>(
            xt, conv_w, conv_b, dcn_w, dcn_b, out);
    } else {
        deform_fused_kernel<<<(total + 255) / 256, 256, 0, stream>>>(
            x, conv_w, conv_b, dcn_w, dcn_b, out);
    }
}